// Round 6
// baseline (173.679 us; speedup 1.0000x reference)
//
#include <hip/hip_runtime.h>

typedef short bf16x8 __attribute__((ext_vector_type(8)));
typedef float f32x4  __attribute__((ext_vector_type(4)));

#define Sx 9216              // 96*96
#define ROWW 96              // x width of xo_t
#define WB_USHORTS 331776    // 162 steps * 4 mt * 64 lanes * 8
#define OW 94
#define XO_USHORTS ((size_t)8 * 96 * ROWW * 576)         // 42,467,328
#define XT_OFF_BYTES (2 * (size_t)WB_USHORTS + 2 * XO_USHORTS) // 85,598,208
#define NEED_NEW (XT_OFF_BYTES + (size_t)8 * Sx * 64 * 4)      // 104,472,576

__device__ __forceinline__ unsigned short bf16r(float f) {
    unsigned int u = __float_as_uint(f);
    u += 0x7fffu + ((u >> 16) & 1u);
    return (unsigned short)(u >> 16);
}

__device__ __forceinline__ void gload16(const void* g, void* l) {
    __builtin_amdgcn_global_load_lds(
        (const __attribute__((address_space(1))) void*)g,
        (__attribute__((address_space(3))) void*)l, 16, 0, 0);
}

// ---- Weight prep: fp32 conv_w -> bf16, K permuted as q' = chr*64 + ci ----
__global__ __launch_bounds__(256)
void wprep_k(const float* __restrict__ w, unsigned short* __restrict__ Wb) {
    int id = blockIdx.x * 256 + threadIdx.x;       // 0..41471
    if (id >= 162 * 4 * 64) return;
    int lane = id & 63;
    int fm   = id >> 6;          // step*4 + mt
    int mt   = fm & 3;
    int step = fm >> 2;
    int qc   = step / 18;
    int rs   = step - qc * 18;
    int t    = rs >> 1;
    int q32  = rs & 1;
    int o    = mt * 16 + (lane & 15);
    int cib  = q32 * 32 + (lane >> 4) * 8;
    unsigned short v[8];
    #pragma unroll
    for (int j = 0; j < 8; ++j) {
        int qorig = (cib + j) * 9 + qc;
        v[j] = bf16r(w[(size_t)o * 5184 + qorig * 9 + t]);
    }
    uint4 u;
    u.x = v[0] | ((unsigned)v[1] << 16);
    u.y = v[2] | ((unsigned)v[3] << 16);
    u.z = v[4] | ((unsigned)v[5] << 16);
    u.w = v[6] | ((unsigned)v[7] << 16);
    *(uint4*)(Wb + (size_t)id * 8) = u;
}

// ---- Transpose x: [b][ci][pos] -> xt [b][pos][ci]  (channel-last) ----
__global__ __launch_bounds__(256)
void xt_k(const float* __restrict__ x, float* __restrict__ xt) {
    __shared__ float t[64][65];
    const int tid = threadIdx.x;
    const int r2b = blockIdx.x * 64;
    const int b   = blockIdx.y;
    const int qq  = tid >> 6;      // 0..3
    const int ll  = tid & 63;
    #pragma unroll
    for (int cc = 0; cc < 16; ++cc) {
        int ci = cc * 4 + qq;
        t[ci][ll] = x[((size_t)(b * 64 + ci)) * Sx + r2b + ll];
    }
    __syncthreads();
    #pragma unroll
    for (int rr = 0; rr < 16; ++rr) {
        int r2l = rr * 4 + qq;
        xt[((size_t)b * Sx + r2b + r2l) * 64 + ll] = t[ll][r2l];
    }
}

// ---- Shared decode (phase 1 of both gather variants) ----
__device__ __forceinline__ void decode_phase1(
        const float* __restrict__ ob, int x0b, int y,
        int (*sA)[288], float (*sW)[288], int tid) {
    for (int e = tid; e < 288; e += 256) {
        int chr = e >> 5;
        int xl  = e & 31;
        int r2  = y * 96 + x0b + xl;
        int n   = r2 % 9;                 // 9216 % 9 == 0
        int r   = chr * 1024 + r2 / 9;
        float q2[2];
        #pragma unroll
        for (int c2 = 0; c2 < 2; ++c2) {
            int k    = n + 9 * c2;
            int f    = k * Sx + r;
            int nn   = f / 18432;
            int t    = f - nn * 18432;
            int comp = t & 1;
            int pos  = t >> 1;
            int nd3  = nn / 3;
            float gg = comp ? (float)(nn - nd3 * 3) : (float)nd3;
            q2[c2] = gg + ob[(size_t)(2 * nn + comp) * Sx + pos];
        }
        float qx = fminf(fmaxf(q2[0], 0.f), 97.f);
        float qy = fminf(fmaxf(q2[1], 0.f), 97.f);
        int x0 = (int)qx; if (x0 > 97) x0 = 97;
        int y0 = (int)qy; if (y0 > 97) y0 = 97;
        float fx = qx - (float)x0;
        float fy = qy - (float)y0;
        int x1 = x0 + 1; if (x1 > 97) x1 = 97;
        int y1 = y0 + 1; if (y1 > 97) y1 = 97;
        int ix0 = x0 - 1, ix1 = x1 - 1, iy0 = y0 - 1, iy1 = y1 - 1;
        float vx0 = (ix0 >= 0 && ix0 < 96) ? 1.f : 0.f;
        float vx1 = (ix1 >= 0 && ix1 < 96) ? 1.f : 0.f;
        float vy0 = (iy0 >= 0 && iy0 < 96) ? 1.f : 0.f;
        float vy1 = (iy1 >= 0 && iy1 < 96) ? 1.f : 0.f;
        int cx0 = min(max(ix0, 0), 95), cx1 = min(max(ix1, 0), 95);
        int cy0 = min(max(iy0, 0), 95), cy1 = min(max(iy1, 0), 95);
        sW[0][e] = (1.f - fx) * (1.f - fy) * vx0 * vy0;
        sW[1][e] = fx * (1.f - fy) * vx1 * vy0;
        sW[2][e] = (1.f - fx) * fy * vx0 * vy1;
        sW[3][e] = fx * fy * vx1 * vy1;
        sA[0][e] = cy0 * 96 + cx0;
        sA[1][e] = cy0 * 96 + cx1;
        sA[2][e] = cy1 * 96 + cx0;
        sA[3][e] = cy1 * 96 + cx1;
    }
}

// ---- Gather: wave-per-entry, coalesced taps from channel-last xt ----
__global__ __launch_bounds__(256, 4)
void gather_xt(const float* __restrict__ xt, const float* __restrict__ off,
               unsigned short* __restrict__ xo) {
    __shared__ int   sA[4][288];
    __shared__ float sW[4][288];
    const int tid = threadIdx.x;
    const int x0b = blockIdx.x * 32;
    const int y   = blockIdx.y;
    const int b   = blockIdx.z;
    decode_phase1(off + (size_t)b * 18 * Sx, x0b, y, sA, sW, tid);
    __syncthreads();

    const int lane = tid & 63;
    const int wv   = tid >> 6;
    const float* xtb = xt + (size_t)b * Sx * 64 + lane;
    unsigned short* xob =
        xo + ((size_t)(b * 96 + y) * ROWW + x0b) * 576 + lane;

    #pragma unroll 4
    for (int i = 0; i < 72; ++i) {
        int e   = wv * 72 + i;
        int chr = e >> 5;
        int xl  = e & 31;
        float v = sW[0][e] * xtb[(size_t)sA[0][e] * 64]
                + sW[1][e] * xtb[(size_t)sA[1][e] * 64]
                + sW[2][e] * xtb[(size_t)sA[2][e] * 64]
                + sW[3][e] * xtb[(size_t)sA[3][e] * 64];
        xob[xl * 576 + chr * 64] = bf16r(v);
    }
}

// ---- Gather (fallback, round-4 path; used only if ws too small) ----
__global__ __launch_bounds__(256, 2)
void gather_fb(const float* __restrict__ x, const float* __restrict__ off,
               unsigned short* __restrict__ xo) {
    __shared__ int   sA[4][288];
    __shared__ float sW[4][288];
    const int tid = threadIdx.x;
    const int x0b = blockIdx.x * 32;
    const int y   = blockIdx.y;
    const int b   = blockIdx.z;
    decode_phase1(off + (size_t)b * 18 * Sx, x0b, y, sA, sW, tid);
    __syncthreads();

    const int xl = tid & 31;
    const int g  = tid >> 5;
    const float* xb = x + (size_t)b * 64 * Sx + (size_t)g * 8 * Sx;
    uint4* dst = (uint4*)(xo + ((size_t)(b * 96 + y) * ROWW + (x0b + xl)) * 576) + g;

    #pragma unroll
    for (int chr = 0; chr < 9; ++chr) {
        int e = chr * 32 + xl;
        int   a00 = sA[0][e], a01 = sA[1][e], a10 = sA[2][e], a11 = sA[3][e];
        float w00 = sW[0][e], w01 = sW[1][e], w10 = sW[2][e], w11 = sW[3][e];
        unsigned short v[8];
        #pragma unroll
        for (int i = 0; i < 8; ++i) {
            const float* xc = xb + (size_t)i * Sx;
            v[i] = bf16r(w00 * xc[a00] + w01 * xc[a01]
                       + w10 * xc[a10] + w11 * xc[a11]);
        }
        uint4 u;
        u.x = v[0] | ((unsigned)v[1] << 16);
        u.y = v[2] | ((unsigned)v[3] << 16);
        u.z = v[4] | ((unsigned)v[5] << 16);
        u.w = v[6] | ((unsigned)v[7] << 16);
        dst[chr * 8] = u;    // q' = chr*64 + g*8
    }
}

// ---- Conv as implicit GEMM on MFMA, double-buffered LDS + counted vmcnt ----
// Block: 3 waves, one oy row. Per qc (K=64 chunk): stage qc+1 into the other
// LDS buffer, s_waitcnt vmcnt(12) (next-stage loads stay in flight), raw
// s_barrier, compute 144 MFMA. XCD swizzle: b = lin&7 so a batch's rows share
// one XCD's L2 (xo rows re-read by oy-1/oy-2 blocks become L2 hits).
__global__ __launch_bounds__(192)
void conv_mfma(const unsigned short* __restrict__ xo,
               const unsigned short* __restrict__ Wb,
               const float* __restrict__ bias,
               float* __restrict__ out) {
    const int lane = threadIdx.x & 63;
    const int wn   = threadIdx.x >> 6;   // 0..2 (= staged ky row)
    const int lin  = blockIdx.x + 94 * blockIdx.y;
    const int b    = lin & 7;            // XCD-contiguous batches
    const int oy   = lin >> 3;           // 0..93

    __shared__ unsigned short tile[2 * 18432 + 128];  // 2 bufs + bleed pad
    char* tb = (char*)tile;

    f32x4 acc[4][2];
    #pragma unroll
    for (int m = 0; m < 4; ++m)
        #pragma unroll
        for (int nfl = 0; nfl < 2; ++nfl)
            acc[m][nfl] = (f32x4){0.f, 0.f, 0.f, 0.f};

    const bf16x8* W8 = (const bf16x8*)Wb;

    const int xl  = lane >> 3;          // 0..7
    const int sl  = lane & 7;
    const int swz = (sl ^ xl) * 8;      // pre-swizzled q-slot (elems)
    const size_t growbase = (size_t)(b * 96 + oy + wn) * (ROWW * 576);

    // prologue: stage qc=0 into buffer 0
    {
        unsigned short* lrow = tile + wn * 6144;
        #pragma unroll
        for (int i = 0; i < 12; ++i)
            gload16(xo + growbase + (size_t)(i * 8 + xl) * 576 + swz,
                    lrow + i * 512);
    }

    for (int qc = 0; qc < 9; ++qc) {
        const int p = qc & 1;
        if (qc < 8) {   // stage qc+1 into other buffer; stays in flight
            unsigned short* lrow = tile + (p ^ 1) * 18432 + wn * 6144;
            #pragma unroll
            for (int i = 0; i < 12; ++i)
                gload16(xo + growbase + (size_t)(i * 8 + xl) * 576
                           + (qc + 1) * 64 + swz,
                        lrow + i * 512);
        }
        __builtin_amdgcn_sched_barrier(0);
        if (qc < 8) asm volatile("s_waitcnt vmcnt(12)" ::: "memory");
        else        asm volatile("s_waitcnt vmcnt(0)"  ::: "memory");
        __builtin_amdgcn_s_barrier();
        __builtin_amdgcn_sched_barrier(0);

        const int poff = p * 36864;    // byte offset of current buffer
        #pragma unroll
        for (int st = 0; st < 18; ++st) {
            const int t = st >> 1, q32 = st & 1;
            const int ky = t / 3, kx = t - (t / 3) * 3;
            const int step = qc * 18 + t * 2 + q32;
            bf16x8 a0 = W8[(step * 4 + 0) * 64 + lane];
            bf16x8 a1 = W8[(step * 4 + 1) * 64 + lane];
            bf16x8 a2 = W8[(step * 4 + 2) * 64 + lane];
            bf16x8 a3 = W8[(step * 4 + 3) * 64 + lane];
            bf16x8 bf[2];
            #pragma unroll
            for (int nfl = 0; nfl < 2; ++nfl) {
                int xpix = (wn * 2 + nfl) * 16 + (lane & 15) + kx;
                int slot = (q32 * 4 + (lane >> 4)) ^ (xpix & 7);
                bf[nfl] = *(const bf16x8*)(tb + poff + ky * 12288
                                             + xpix * 128 + slot * 16);
            }
            __builtin_amdgcn_s_setprio(1);
            acc[0][0] = __builtin_amdgcn_mfma_f32_16x16x32_bf16(a0, bf[0], acc[0][0], 0, 0, 0);
            acc[0][1] = __builtin_amdgcn_mfma_f32_16x16x32_bf16(a0, bf[1], acc[0][1], 0, 0, 0);
            acc[1][0] = __builtin_amdgcn_mfma_f32_16x16x32_bf16(a1, bf[0], acc[1][0], 0, 0, 0);
            acc[1][1] = __builtin_amdgcn_mfma_f32_16x16x32_bf16(a1, bf[1], acc[1][1], 0, 0, 0);
            acc[2][0] = __builtin_amdgcn_mfma_f32_16x16x32_bf16(a2, bf[0], acc[2][0], 0, 0, 0);
            acc[2][1] = __builtin_amdgcn_mfma_f32_16x16x32_bf16(a2, bf[1], acc[2][1], 0, 0, 0);
            acc[3][0] = __builtin_amdgcn_mfma_f32_16x16x32_bf16(a3, bf[0], acc[3][0], 0, 0, 0);
            acc[3][1] = __builtin_amdgcn_mfma_f32_16x16x32_bf16(a3, bf[1], acc[3][1], 0, 0, 0);
            __builtin_amdgcn_s_setprio(0);
        }
        __builtin_amdgcn_sched_barrier(0);
        __builtin_amdgcn_s_barrier();   // don't restage until all waves done
    }

    // Epilogue: C/D layout col=lane&15 (pixel), row=(lane>>4)*4+j (o in tile)
    #pragma unroll
    for (int m = 0; m < 4; ++m) {
        #pragma unroll
        for (int nfl = 0; nfl < 2; ++nfl) {
            int ox = (wn * 2 + nfl) * 16 + (lane & 15);
            if (ox < OW) {
                #pragma unroll
                for (int j = 0; j < 4; ++j) {
                    int o = m * 16 + (lane >> 4) * 4 + j;
                    out[(((size_t)b * 64 + o) * OW + oy) * OW + ox] = acc[m][nfl][j] + bias[o];
                }
            }
        }
    }
}

extern "C" void kernel_launch(void* const* d_in, const int* in_sizes, int n_in,
                              void* d_out, int out_size, void* d_ws, size_t ws_size,
                              hipStream_t stream) {
    const float* x    = (const float*)d_in[0];
    const float* off  = (const float*)d_in[1];
    const float* w    = (const float*)d_in[2];
    const float* bias = (const float*)d_in[3];
    unsigned short* ws16 = (unsigned short*)d_ws;
    unsigned short* Wb   = ws16;                  // 663,552 B
    unsigned short* xo   = ws16 + WB_USHORTS;     // 84.9 MB

    wprep_k<<<162, 256, 0, stream>>>(w, Wb);
    if (ws_size >= NEED_NEW) {
        float* xt = (float*)((char*)d_ws + XT_OFF_BYTES);   // 18.9 MB
        xt_k<<<dim3(144, 8), 256, 0, stream>>>(x, xt);
        gather_xt<<<dim3(3, 96, 8), 256, 0, stream>>>(xt, off, xo);
    } else {
        gather_fb<<<dim3(3, 96, 8), 256, 0, stream>>>(x, off, xo);
    }
    conv_mfma<<<dim3(94, 8), 192, 0, stream>>>(xo, Wb, bias, (float*)d_out);
}

// Round 7
// 134.783 us; speedup vs baseline: 1.2886x; 1.2886x over previous
//
#include <hip/hip_runtime.h>

typedef short bf16x8 __attribute__((ext_vector_type(8)));
typedef float f32x4  __attribute__((ext_vector_type(4)));

#define Sx 9216              // 96*96
#define ROWW 96              // x width of xo_t
#define WB_USHORTS 331776    // 162 steps * 4 mt * 64 lanes * 8
#define OW 94
#define XO_USHORTS ((size_t)8 * 96 * ROWW * 576)         // 42,467,328
#define XT_OFF_BYTES (2 * (size_t)WB_USHORTS + 2 * XO_USHORTS) // 85,598,208
#define NEED_NEW (XT_OFF_BYTES + (size_t)8 * Sx * 64 * 4)      // 104,472,576

__device__ __forceinline__ unsigned short bf16r(float f) {
    unsigned int u = __float_as_uint(f);
    u += 0x7fffu + ((u >> 16) & 1u);
    return (unsigned short)(u >> 16);
}

__device__ __forceinline__ void gload16(const void* g, void* l) {
    __builtin_amdgcn_global_load_lds(
        (const __attribute__((address_space(1))) void*)g,
        (__attribute__((address_space(3))) void*)l, 16, 0, 0);
}

// ---- Weight prep: fp32 conv_w -> bf16, K permuted as q' = chr*64 + ci ----
__global__ __launch_bounds__(256)
void wprep_k(const float* __restrict__ w, unsigned short* __restrict__ Wb) {
    int id = blockIdx.x * 256 + threadIdx.x;       // 0..41471
    if (id >= 162 * 4 * 64) return;
    int lane = id & 63;
    int fm   = id >> 6;          // step*4 + mt
    int mt   = fm & 3;
    int step = fm >> 2;
    int qc   = step / 18;
    int rs   = step - qc * 18;
    int t    = rs >> 1;
    int q32  = rs & 1;
    int o    = mt * 16 + (lane & 15);
    int cib  = q32 * 32 + (lane >> 4) * 8;
    unsigned short v[8];
    #pragma unroll
    for (int j = 0; j < 8; ++j) {
        int qorig = (cib + j) * 9 + qc;
        v[j] = bf16r(w[(size_t)o * 5184 + qorig * 9 + t]);
    }
    uint4 u;
    u.x = v[0] | ((unsigned)v[1] << 16);
    u.y = v[2] | ((unsigned)v[3] << 16);
    u.z = v[4] | ((unsigned)v[5] << 16);
    u.w = v[6] | ((unsigned)v[7] << 16);
    *(uint4*)(Wb + (size_t)id * 8) = u;
}

// ---- Transpose x: [b][ci][pos] -> xt [b][pos][ci]  (channel-last) ----
__global__ __launch_bounds__(256)
void xt_k(const float* __restrict__ x, float* __restrict__ xt) {
    __shared__ float t[64][65];
    const int tid = threadIdx.x;
    const int r2b = blockIdx.x * 64;
    const int b   = blockIdx.y;
    const int qq  = tid >> 6;      // 0..3
    const int ll  = tid & 63;
    #pragma unroll
    for (int cc = 0; cc < 16; ++cc) {
        int ci = cc * 4 + qq;
        t[ci][ll] = x[((size_t)(b * 64 + ci)) * Sx + r2b + ll];
    }
    __syncthreads();
    #pragma unroll
    for (int rr = 0; rr < 16; ++rr) {
        int r2l = rr * 4 + qq;
        xt[((size_t)b * Sx + r2b + r2l) * 64 + ll] = t[ll][r2l];
    }
}

// ---- Shared decode (phase 1 of both gather variants) ----
__device__ __forceinline__ void decode_phase1(
        const float* __restrict__ ob, int x0b, int y,
        int (*sA)[288], float (*sW)[288], int tid) {
    for (int e = tid; e < 288; e += 256) {
        int chr = e >> 5;
        int xl  = e & 31;
        int r2  = y * 96 + x0b + xl;
        int n   = r2 % 9;                 // 9216 % 9 == 0
        int r   = chr * 1024 + r2 / 9;
        float q2[2];
        #pragma unroll
        for (int c2 = 0; c2 < 2; ++c2) {
            int k    = n + 9 * c2;
            int f    = k * Sx + r;
            int nn   = f / 18432;
            int t    = f - nn * 18432;
            int comp = t & 1;
            int pos  = t >> 1;
            int nd3  = nn / 3;
            float gg = comp ? (float)(nn - nd3 * 3) : (float)nd3;
            q2[c2] = gg + ob[(size_t)(2 * nn + comp) * Sx + pos];
        }
        float qx = fminf(fmaxf(q2[0], 0.f), 97.f);
        float qy = fminf(fmaxf(q2[1], 0.f), 97.f);
        int x0 = (int)qx; if (x0 > 97) x0 = 97;
        int y0 = (int)qy; if (y0 > 97) y0 = 97;
        float fx = qx - (float)x0;
        float fy = qy - (float)y0;
        int x1 = x0 + 1; if (x1 > 97) x1 = 97;
        int y1 = y0 + 1; if (y1 > 97) y1 = 97;
        int ix0 = x0 - 1, ix1 = x1 - 1, iy0 = y0 - 1, iy1 = y1 - 1;
        float vx0 = (ix0 >= 0 && ix0 < 96) ? 1.f : 0.f;
        float vx1 = (ix1 >= 0 && ix1 < 96) ? 1.f : 0.f;
        float vy0 = (iy0 >= 0 && iy0 < 96) ? 1.f : 0.f;
        float vy1 = (iy1 >= 0 && iy1 < 96) ? 1.f : 0.f;
        int cx0 = min(max(ix0, 0), 95), cx1 = min(max(ix1, 0), 95);
        int cy0 = min(max(iy0, 0), 95), cy1 = min(max(iy1, 0), 95);
        sW[0][e] = (1.f - fx) * (1.f - fy) * vx0 * vy0;
        sW[1][e] = fx * (1.f - fy) * vx1 * vy0;
        sW[2][e] = (1.f - fx) * fy * vx0 * vy1;
        sW[3][e] = fx * fy * vx1 * vy1;
        sA[0][e] = cy0 * 96 + cx0;
        sA[1][e] = cy0 * 96 + cx1;
        sA[2][e] = cy1 * 96 + cx0;
        sA[3][e] = cy1 * 96 + cx1;
    }
}

// ---- Gather: wave-per-entry, coalesced taps from channel-last xt ----
__global__ __launch_bounds__(256, 4)
void gather_xt(const float* __restrict__ xt, const float* __restrict__ off,
               unsigned short* __restrict__ xo) {
    __shared__ int   sA[4][288];
    __shared__ float sW[4][288];
    const int tid = threadIdx.x;
    const int x0b = blockIdx.x * 32;
    const int y   = blockIdx.y;
    const int b   = blockIdx.z;
    decode_phase1(off + (size_t)b * 18 * Sx, x0b, y, sA, sW, tid);
    __syncthreads();

    const int lane = tid & 63;
    const int wv   = tid >> 6;
    const float* xtb = xt + (size_t)b * Sx * 64 + lane;
    unsigned short* xob =
        xo + ((size_t)(b * 96 + y) * ROWW + x0b) * 576 + lane;

    #pragma unroll 4
    for (int i = 0; i < 72; ++i) {
        int e   = wv * 72 + i;
        int chr = e >> 5;
        int xl  = e & 31;
        float v = sW[0][e] * xtb[(size_t)sA[0][e] * 64]
                + sW[1][e] * xtb[(size_t)sA[1][e] * 64]
                + sW[2][e] * xtb[(size_t)sA[2][e] * 64]
                + sW[3][e] * xtb[(size_t)sA[3][e] * 64];
        xob[xl * 576 + chr * 64] = bf16r(v);
    }
}

// ---- Gather (fallback, round-4 path; used only if ws too small) ----
__global__ __launch_bounds__(256, 2)
void gather_fb(const float* __restrict__ x, const float* __restrict__ off,
               unsigned short* __restrict__ xo) {
    __shared__ int   sA[4][288];
    __shared__ float sW[4][288];
    const int tid = threadIdx.x;
    const int x0b = blockIdx.x * 32;
    const int y   = blockIdx.y;
    const int b   = blockIdx.z;
    decode_phase1(off + (size_t)b * 18 * Sx, x0b, y, sA, sW, tid);
    __syncthreads();

    const int xl = tid & 31;
    const int g  = tid >> 5;
    const float* xb = x + (size_t)b * 64 * Sx + (size_t)g * 8 * Sx;
    uint4* dst = (uint4*)(xo + ((size_t)(b * 96 + y) * ROWW + (x0b + xl)) * 576) + g;

    #pragma unroll
    for (int chr = 0; chr < 9; ++chr) {
        int e = chr * 32 + xl;
        int   a00 = sA[0][e], a01 = sA[1][e], a10 = sA[2][e], a11 = sA[3][e];
        float w00 = sW[0][e], w01 = sW[1][e], w10 = sW[2][e], w11 = sW[3][e];
        unsigned short v[8];
        #pragma unroll
        for (int i = 0; i < 8; ++i) {
            const float* xc = xb + (size_t)i * Sx;
            v[i] = bf16r(w00 * xc[a00] + w01 * xc[a01]
                       + w10 * xc[a10] + w11 * xc[a11]);
        }
        uint4 u;
        u.x = v[0] | ((unsigned)v[1] << 16);
        u.y = v[2] | ((unsigned)v[3] << 16);
        u.z = v[4] | ((unsigned)v[5] << 16);
        u.w = v[6] | ((unsigned)v[7] << 16);
        dst[chr * 8] = u;    // q' = chr*64 + g*8
    }
}

// ---- Conv as implicit GEMM: 2 oy rows x 96 px per block, 3 waves.
// Wave wn owns x-cols [wn*32, wn*32+32) of BOTH rows: per step 4 A-frags feed
// 16 MFMA (A-load frequency halved vs 1-row tile). Single-buffered LDS
// [4 rows][96x][64q], stage -> vmcnt(0) -> barrier -> compute per qc.
// XCD swizzle: b = lin&7 (keeps one batch's xo in one XCD's L2).
__global__ __launch_bounds__(192, 3)
void conv_mfma(const unsigned short* __restrict__ xo,
               const unsigned short* __restrict__ Wb,
               const float* __restrict__ bias,
               float* __restrict__ out) {
    const int lane = threadIdx.x & 63;
    const int wn   = threadIdx.x >> 6;   // 0..2
    const int lin  = blockIdx.x + 47 * blockIdx.y;
    const int b    = lin & 7;            // XCD-contiguous batches
    const int p    = lin >> 3;           // 0..46 (oy pair)

    __shared__ unsigned short tile[4 * 6144 + 256];   // 49664 B
    char* tb = (char*)tile;

    f32x4 acc[4][2][2];   // [m][row][xf]
    #pragma unroll
    for (int m = 0; m < 4; ++m)
        #pragma unroll
        for (int ro = 0; ro < 2; ++ro)
            #pragma unroll
            for (int xf = 0; xf < 2; ++xf)
                acc[m][ro][xf] = (f32x4){0.f, 0.f, 0.f, 0.f};

    const bf16x8* W8 = (const bf16x8*)Wb;

    const int xl  = lane >> 3;          // 0..7
    const int sl  = lane & 7;
    const int swz = (sl ^ xl) * 8;      // pre-swizzled q-slot (elems)
    const size_t rowbase = (size_t)(b * 96 + 2 * p) * (ROWW * 576);

    for (int qc = 0; qc < 9; ++qc) {
        if (qc) __syncthreads();        // all waves done reading buffer
        #pragma unroll
        for (int i = 0; i < 16; ++i) {
            int j   = wn * 16 + i;      // 0..47
            int row = j / 12;           // input row 0..3
            int xi  = j - row * 12;     // 0..11
            const unsigned short* src =
                xo + rowbase + (size_t)row * (ROWW * 576)
                   + (size_t)(xi * 8 + xl) * 576 + qc * 64 + swz;
            gload16(src, tile + row * 6144 + xi * 512);
        }
        asm volatile("s_waitcnt vmcnt(0)" ::: "memory");
        __syncthreads();

        #pragma unroll
        for (int st = 0; st < 18; ++st) {
            const int t = st >> 1, q32 = st & 1;
            const int ky = t / 3, kx = t - (t / 3) * 3;
            const int step = qc * 18 + st;
            bf16x8 a0 = W8[(step * 4 + 0) * 64 + lane];
            bf16x8 a1 = W8[(step * 4 + 1) * 64 + lane];
            bf16x8 a2 = W8[(step * 4 + 2) * 64 + lane];
            bf16x8 a3 = W8[(step * 4 + 3) * 64 + lane];
            bf16x8 bf[2][2];
            #pragma unroll
            for (int ro = 0; ro < 2; ++ro) {
                #pragma unroll
                for (int xf = 0; xf < 2; ++xf) {
                    int xpix = wn * 32 + xf * 16 + (lane & 15) + kx;
                    int slot = (q32 * 4 + (lane >> 4)) ^ (xpix & 7);
                    bf[ro][xf] = *(const bf16x8*)(tb + (ro + ky) * 12288
                                                    + xpix * 128 + slot * 16);
                }
            }
            __builtin_amdgcn_s_setprio(1);
            #pragma unroll
            for (int ro = 0; ro < 2; ++ro) {
                #pragma unroll
                for (int xf = 0; xf < 2; ++xf) {
                    acc[0][ro][xf] = __builtin_amdgcn_mfma_f32_16x16x32_bf16(a0, bf[ro][xf], acc[0][ro][xf], 0, 0, 0);
                    acc[1][ro][xf] = __builtin_amdgcn_mfma_f32_16x16x32_bf16(a1, bf[ro][xf], acc[1][ro][xf], 0, 0, 0);
                    acc[2][ro][xf] = __builtin_amdgcn_mfma_f32_16x16x32_bf16(a2, bf[ro][xf], acc[2][ro][xf], 0, 0, 0);
                    acc[3][ro][xf] = __builtin_amdgcn_mfma_f32_16x16x32_bf16(a3, bf[ro][xf], acc[3][ro][xf], 0, 0, 0);
                }
            }
            __builtin_amdgcn_s_setprio(0);
        }
    }

    // Epilogue: C/D layout col=lane&15 (pixel), row=(lane>>4)*4+j (o in tile)
    #pragma unroll
    for (int m = 0; m < 4; ++m) {
        #pragma unroll
        for (int ro = 0; ro < 2; ++ro) {
            #pragma unroll
            for (int xf = 0; xf < 2; ++xf) {
                int ox = wn * 32 + xf * 16 + (lane & 15);
                if (ox < OW) {
                    int oyr = 2 * p + ro;
                    #pragma unroll
                    for (int j = 0; j < 4; ++j) {
                        int o = m * 16 + (lane >> 4) * 4 + j;
                        out[(((size_t)b * 64 + o) * OW + oyr) * OW + ox] =
                            acc[m][ro][xf][j] + bias[o];
                    }
                }
            }
        }
    }
}

extern "C" void kernel_launch(void* const* d_in, const int* in_sizes, int n_in,
                              void* d_out, int out_size, void* d_ws, size_t ws_size,
                              hipStream_t stream) {
    const float* x    = (const float*)d_in[0];
    const float* off  = (const float*)d_in[1];
    const float* w    = (const float*)d_in[2];
    const float* bias = (const float*)d_in[3];
    unsigned short* ws16 = (unsigned short*)d_ws;
    unsigned short* Wb   = ws16;                  // 663,552 B
    unsigned short* xo   = ws16 + WB_USHORTS;     // 84.9 MB

    wprep_k<<<162, 256, 0, stream>>>(w, Wb);
    if (ws_size >= NEED_NEW) {
        float* xt = (float*)((char*)d_ws + XT_OFF_BYTES);   // 18.9 MB
        xt_k<<<dim3(144, 8), 256, 0, stream>>>(x, xt);
        gather_xt<<<dim3(3, 96, 8), 256, 0, stream>>>(xt, off, xo);
    } else {
        gather_fb<<<dim3(3, 96, 8), 256, 0, stream>>>(x, off, xo);
    }
    conv_mfma<<<dim3(47, 8), 192, 0, stream>>>(xo, Wb, bias, (float*)d_out);
}

// Round 8
// 123.656 us; speedup vs baseline: 1.4045x; 1.0900x over previous
//
#include <hip/hip_runtime.h>

typedef short bf16x8 __attribute__((ext_vector_type(8)));
typedef float f32x4  __attribute__((ext_vector_type(4)));

#define Sx 9216              // 96*96
#define ROWW 96              // x width of xo_t
#define WB_USHORTS 331776    // 162 steps * 4 mt * 64 lanes * 8
#define OW 94
#define XO_USHORTS ((size_t)8 * 96 * ROWW * 576)         // 42,467,328
#define XT_OFF_BYTES (2 * (size_t)WB_USHORTS + 2 * XO_USHORTS) // 85,598,208
#define NEED_NEW (XT_OFF_BYTES + (size_t)8 * Sx * 64 * 4)      // 104,472,576

__device__ __forceinline__ unsigned short bf16r(float f) {
    unsigned int u = __float_as_uint(f);
    u += 0x7fffu + ((u >> 16) & 1u);
    return (unsigned short)(u >> 16);
}

__device__ __forceinline__ void gload16(const void* g, void* l) {
    __builtin_amdgcn_global_load_lds(
        (const __attribute__((address_space(1))) void*)g,
        (__attribute__((address_space(3))) void*)l, 16, 0, 0);
}

// ---- Weight prep: fp32 conv_w -> bf16, K permuted as q' = chr*64 + ci ----
__global__ __launch_bounds__(256)
void wprep_k(const float* __restrict__ w, unsigned short* __restrict__ Wb) {
    int id = blockIdx.x * 256 + threadIdx.x;       // 0..41471
    if (id >= 162 * 4 * 64) return;
    int lane = id & 63;
    int fm   = id >> 6;          // step*4 + mt
    int mt   = fm & 3;
    int step = fm >> 2;
    int qc   = step / 18;
    int rs   = step - qc * 18;
    int t    = rs >> 1;
    int q32  = rs & 1;
    int o    = mt * 16 + (lane & 15);
    int cib  = q32 * 32 + (lane >> 4) * 8;
    unsigned short v[8];
    #pragma unroll
    for (int j = 0; j < 8; ++j) {
        int qorig = (cib + j) * 9 + qc;
        v[j] = bf16r(w[(size_t)o * 5184 + qorig * 9 + t]);
    }
    uint4 u;
    u.x = v[0] | ((unsigned)v[1] << 16);
    u.y = v[2] | ((unsigned)v[3] << 16);
    u.z = v[4] | ((unsigned)v[5] << 16);
    u.w = v[6] | ((unsigned)v[7] << 16);
    *(uint4*)(Wb + (size_t)id * 8) = u;
}

// ---- Transpose x: [b][ci][pos] -> xt [b][pos][ci]  (channel-last) ----
__global__ __launch_bounds__(256)
void xt_k(const float* __restrict__ x, float* __restrict__ xt) {
    __shared__ float t[64][65];
    const int tid = threadIdx.x;
    const int r2b = blockIdx.x * 64;
    const int b   = blockIdx.y;
    const int qq  = tid >> 6;      // 0..3
    const int ll  = tid & 63;
    #pragma unroll
    for (int cc = 0; cc < 16; ++cc) {
        int ci = cc * 4 + qq;
        t[ci][ll] = x[((size_t)(b * 64 + ci)) * Sx + r2b + ll];
    }
    __syncthreads();
    #pragma unroll
    for (int rr = 0; rr < 16; ++rr) {
        int r2l = rr * 4 + qq;
        xt[((size_t)b * Sx + r2b + r2l) * 64 + ll] = t[ll][r2l];
    }
}

// ---- Shared decode (phase 1 of both gather variants) ----
__device__ __forceinline__ void decode_phase1(
        const float* __restrict__ ob, int x0b, int y,
        int (*sA)[288], float (*sW)[288], int tid) {
    for (int e = tid; e < 288; e += 256) {
        int chr = e >> 5;
        int xl  = e & 31;
        int r2  = y * 96 + x0b + xl;
        int n   = r2 % 9;                 // 9216 % 9 == 0
        int r   = chr * 1024 + r2 / 9;
        float q2[2];
        #pragma unroll
        for (int c2 = 0; c2 < 2; ++c2) {
            int k    = n + 9 * c2;
            int f    = k * Sx + r;
            int nn   = f / 18432;
            int t    = f - nn * 18432;
            int comp = t & 1;
            int pos  = t >> 1;
            int nd3  = nn / 3;
            float gg = comp ? (float)(nn - nd3 * 3) : (float)nd3;
            q2[c2] = gg + ob[(size_t)(2 * nn + comp) * Sx + pos];
        }
        float qx = fminf(fmaxf(q2[0], 0.f), 97.f);
        float qy = fminf(fmaxf(q2[1], 0.f), 97.f);
        int x0 = (int)qx; if (x0 > 97) x0 = 97;
        int y0 = (int)qy; if (y0 > 97) y0 = 97;
        float fx = qx - (float)x0;
        float fy = qy - (float)y0;
        int x1 = x0 + 1; if (x1 > 97) x1 = 97;
        int y1 = y0 + 1; if (y1 > 97) y1 = 97;
        int ix0 = x0 - 1, ix1 = x1 - 1, iy0 = y0 - 1, iy1 = y1 - 1;
        float vx0 = (ix0 >= 0 && ix0 < 96) ? 1.f : 0.f;
        float vx1 = (ix1 >= 0 && ix1 < 96) ? 1.f : 0.f;
        float vy0 = (iy0 >= 0 && iy0 < 96) ? 1.f : 0.f;
        float vy1 = (iy1 >= 0 && iy1 < 96) ? 1.f : 0.f;
        int cx0 = min(max(ix0, 0), 95), cx1 = min(max(ix1, 0), 95);
        int cy0 = min(max(iy0, 0), 95), cy1 = min(max(iy1, 0), 95);
        sW[0][e] = (1.f - fx) * (1.f - fy) * vx0 * vy0;
        sW[1][e] = fx * (1.f - fy) * vx1 * vy0;
        sW[2][e] = (1.f - fx) * fy * vx0 * vy1;
        sW[3][e] = fx * fy * vx1 * vy1;
        sA[0][e] = cy0 * 96 + cx0;
        sA[1][e] = cy0 * 96 + cx1;
        sA[2][e] = cy1 * 96 + cx0;
        sA[3][e] = cy1 * 96 + cx1;
    }
}

// ---- Gather: wave-per-entry, coalesced taps from channel-last xt ----
__global__ __launch_bounds__(256, 4)
void gather_xt(const float* __restrict__ xt, const float* __restrict__ off,
               unsigned short* __restrict__ xo) {
    __shared__ int   sA[4][288];
    __shared__ float sW[4][288];
    const int tid = threadIdx.x;
    const int x0b = blockIdx.x * 32;
    const int y   = blockIdx.y;
    const int b   = blockIdx.z;
    decode_phase1(off + (size_t)b * 18 * Sx, x0b, y, sA, sW, tid);
    __syncthreads();

    const int lane = tid & 63;
    const int wv   = tid >> 6;
    const float* xtb = xt + (size_t)b * Sx * 64 + lane;
    unsigned short* xob =
        xo + ((size_t)(b * 96 + y) * ROWW + x0b) * 576 + lane;

    #pragma unroll 4
    for (int i = 0; i < 72; ++i) {
        int e   = wv * 72 + i;
        int chr = e >> 5;
        int xl  = e & 31;
        float v = sW[0][e] * xtb[(size_t)sA[0][e] * 64]
                + sW[1][e] * xtb[(size_t)sA[1][e] * 64]
                + sW[2][e] * xtb[(size_t)sA[2][e] * 64]
                + sW[3][e] * xtb[(size_t)sA[3][e] * 64];
        xob[xl * 576 + chr * 64] = bf16r(v);
    }
}

// ---- Gather (fallback, round-4 path; used only if ws too small) ----
__global__ __launch_bounds__(256, 2)
void gather_fb(const float* __restrict__ x, const float* __restrict__ off,
               unsigned short* __restrict__ xo) {
    __shared__ int   sA[4][288];
    __shared__ float sW[4][288];
    const int tid = threadIdx.x;
    const int x0b = blockIdx.x * 32;
    const int y   = blockIdx.y;
    const int b   = blockIdx.z;
    decode_phase1(off + (size_t)b * 18 * Sx, x0b, y, sA, sW, tid);
    __syncthreads();

    const int xl = tid & 31;
    const int g  = tid >> 5;
    const float* xb = x + (size_t)b * 64 * Sx + (size_t)g * 8 * Sx;
    uint4* dst = (uint4*)(xo + ((size_t)(b * 96 + y) * ROWW + (x0b + xl)) * 576) + g;

    #pragma unroll
    for (int chr = 0; chr < 9; ++chr) {
        int e = chr * 32 + xl;
        int   a00 = sA[0][e], a01 = sA[1][e], a10 = sA[2][e], a11 = sA[3][e];
        float w00 = sW[0][e], w01 = sW[1][e], w10 = sW[2][e], w11 = sW[3][e];
        unsigned short v[8];
        #pragma unroll
        for (int i = 0; i < 8; ++i) {
            const float* xc = xb + (size_t)i * Sx;
            v[i] = bf16r(w00 * xc[a00] + w01 * xc[a01]
                       + w10 * xc[a10] + w11 * xc[a11]);
        }
        uint4 u;
        u.x = v[0] | ((unsigned)v[1] << 16);
        u.y = v[2] | ((unsigned)v[3] << 16);
        u.z = v[4] | ((unsigned)v[5] << 16);
        u.w = v[6] | ((unsigned)v[7] << 16);
        dst[chr * 8] = u;    // q' = chr*64 + g*8
    }
}

// ---- Conv as implicit GEMM, M-split for load balance ----
// Tile = 2 oy rows x 96 px x 32 out-ch (mh half). Grid = 752 blocks
// (2.94/CU). Block = 3 waves; wave wn owns x-cols [wn*32, wn*32+32) of both
// rows: per step 2 A-frags feed 8 MFMA. Single-buffered LDS [4][96][64].
// Same-tile M-halves are 8 apart in blockIdx -> same XCD -> staged B-tile
// is an L2 hit the second time. b = lin&7 keeps one batch per XCD.
__global__ __launch_bounds__(192, 3)
void conv_mfma(const unsigned short* __restrict__ xo,
               const unsigned short* __restrict__ Wb,
               const float* __restrict__ bias,
               float* __restrict__ out) {
    const int lane = threadIdx.x & 63;
    const int wn   = threadIdx.x >> 6;   // 0..2
    const int lin  = blockIdx.x;         // 0..751
    const int b    = lin & 7;            // XCD-contiguous batches
    const int rest = lin >> 3;           // 0..93
    const int mh   = rest & 1;           // M half (o base = mh*32)
    const int p    = rest >> 1;          // 0..46 (oy pair)

    __shared__ unsigned short tile[4 * 6144 + 256];   // 49664 B
    char* tb = (char*)tile;

    f32x4 acc[2][2][2];   // [m][row][xf]
    #pragma unroll
    for (int m = 0; m < 2; ++m)
        #pragma unroll
        for (int ro = 0; ro < 2; ++ro)
            #pragma unroll
            for (int xf = 0; xf < 2; ++xf)
                acc[m][ro][xf] = (f32x4){0.f, 0.f, 0.f, 0.f};

    const bf16x8* W8 = (const bf16x8*)Wb;

    const int xl  = lane >> 3;          // 0..7
    const int sl  = lane & 7;
    const int swz = (sl ^ xl) * 8;      // pre-swizzled q-slot (elems)
    const size_t rowbase = (size_t)(b * 96 + 2 * p) * (ROWW * 576);

    for (int qc = 0; qc < 9; ++qc) {
        if (qc) __syncthreads();        // all waves done reading buffer
        #pragma unroll
        for (int i = 0; i < 16; ++i) {
            int j   = wn * 16 + i;      // 0..47
            int row = j / 12;           // input row 0..3
            int xi  = j - row * 12;     // 0..11
            const unsigned short* src =
                xo + rowbase + (size_t)row * (ROWW * 576)
                   + (size_t)(xi * 8 + xl) * 576 + qc * 64 + swz;
            gload16(src, tile + row * 6144 + xi * 512);
        }
        asm volatile("s_waitcnt vmcnt(0)" ::: "memory");
        __syncthreads();

        #pragma unroll
        for (int st = 0; st < 18; ++st) {
            const int t = st >> 1, q32 = st & 1;
            const int ky = t / 3, kx = t - (t / 3) * 3;
            const int step = qc * 18 + st;
            bf16x8 a0 = W8[(step * 4 + mh * 2 + 0) * 64 + lane];
            bf16x8 a1 = W8[(step * 4 + mh * 2 + 1) * 64 + lane];
            bf16x8 bf[2][2];
            #pragma unroll
            for (int ro = 0; ro < 2; ++ro) {
                #pragma unroll
                for (int xf = 0; xf < 2; ++xf) {
                    int xpix = wn * 32 + xf * 16 + (lane & 15) + kx;
                    int slot = (q32 * 4 + (lane >> 4)) ^ (xpix & 7);
                    bf[ro][xf] = *(const bf16x8*)(tb + (ro + ky) * 12288
                                                    + xpix * 128 + slot * 16);
                }
            }
            __builtin_amdgcn_s_setprio(1);
            #pragma unroll
            for (int ro = 0; ro < 2; ++ro) {
                #pragma unroll
                for (int xf = 0; xf < 2; ++xf) {
                    acc[0][ro][xf] = __builtin_amdgcn_mfma_f32_16x16x32_bf16(a0, bf[ro][xf], acc[0][ro][xf], 0, 0, 0);
                    acc[1][ro][xf] = __builtin_amdgcn_mfma_f32_16x16x32_bf16(a1, bf[ro][xf], acc[1][ro][xf], 0, 0, 0);
                }
            }
            __builtin_amdgcn_s_setprio(0);
        }
    }

    // Epilogue: C/D layout col=lane&15 (pixel), row=(lane>>4)*4+j (o in tile)
    #pragma unroll
    for (int m = 0; m < 2; ++m) {
        #pragma unroll
        for (int ro = 0; ro < 2; ++ro) {
            #pragma unroll
            for (int xf = 0; xf < 2; ++xf) {
                int ox = wn * 32 + xf * 16 + (lane & 15);
                if (ox < OW) {
                    int oyr = 2 * p + ro;
                    #pragma unroll
                    for (int j = 0; j < 4; ++j) {
                        int o = mh * 32 + m * 16 + (lane >> 4) * 4 + j;
                        out[(((size_t)b * 64 + o) * OW + oyr) * OW + ox] =
                            acc[m][ro][xf][j] + bias[o];
                    }
                }
            }
        }
    }
}

extern "C" void kernel_launch(void* const* d_in, const int* in_sizes, int n_in,
                              void* d_out, int out_size, void* d_ws, size_t ws_size,
                              hipStream_t stream) {
    const float* x    = (const float*)d_in[0];
    const float* off  = (const float*)d_in[1];
    const float* w    = (const float*)d_in[2];
    const float* bias = (const float*)d_in[3];
    unsigned short* ws16 = (unsigned short*)d_ws;
    unsigned short* Wb   = ws16;                  // 663,552 B
    unsigned short* xo   = ws16 + WB_USHORTS;     // 84.9 MB

    wprep_k<<<162, 256, 0, stream>>>(w, Wb);
    if (ws_size >= NEED_NEW) {
        float* xt = (float*)((char*)d_ws + XT_OFF_BYTES);   // 18.9 MB
        xt_k<<<dim3(144, 8), 256, 0, stream>>>(x, xt);
        gather_xt<<<dim3(3, 96, 8), 256, 0, stream>>>(xt, off, xo);
    } else {
        gather_fb<<<dim3(3, 96, 8), 256, 0, stream>>>(x, off, xo);
    }
    conv_mfma<<<752, 192, 0, stream>>>(xo, Wb, bias, (float*)d_out);
}